// Round 2
// baseline (743.943 us; speedup 1.0000x reference)
//
#include <hip/hip_runtime.h>
#include <math.h>

// Problem constants
#define NB    16            // batches
#define NPB   (512*512)     // elements per batch
#define NBINS 64
#define MMB   64            // minmax blocks per batch (grid 1024 = 4/CU)
#define CB    64            // hist chunks per (tensor,batch) -> grid 2*16*64 = 2048
#define EPSF  1e-8f
#define QF    0.84932180517f   // sqrt(0.5*log2(e)); exp(-d^2/2) = exp2(-(q*d)^2)
#define L2E   1.44269504089f   // log2(e)
#define LN2   0.69314718056f

// R19 = R18 resubmit (bench infra failed twice; no counters returned).
// R18: radius-8 LDS-scatter histogram. Dense 64-bin register accumulation
// (R13/R17, 44 us, VALUBusy 70%) wasted 48/64 bins on weights < e^-32 that
// are invisible in fp32. Now each point updates only its 16 neighboring
// rows of a block-shared LDS histogram [96 rows x 64 lane-columns] via
// ds_add_f32. Guard rows 0..14 / 79..93 absorb clamped windows (bins -15..-1,
// 64..78) so real bins stay exact: max dropped weight e^-28 ~ 6e-13.
// Column = lane -> bank = lane%32, fixed 2-way aliasing (free per m136).

#define GROWS 96            // 94 rows used: bin b at row b+15

// ws layout: mmn[1024] | mmx[1024] | hist[2][16][64]

// ---------- pass 1: per-batch block-level min/max (also zeroes hist) ----------
__global__ __launch_bounds__(256) void minmax_k(const float4* __restrict__ tgt,
                                                float* __restrict__ mmn,
                                                float* __restrict__ mmx,
                                                float* __restrict__ hist) {
    const int batch = blockIdx.x / MMB, sub = blockIdx.x % MMB;
    if (sub == 0 && threadIdx.x < 128) {
        const int tens = threadIdx.x >> 6, lane = threadIdx.x & 63;
        hist[(tens * NB + batch) * NBINS + lane] = 0.0f;
    }

    const int F4 = NPB / 4 / MMB;              // 1024 float4 per block
    const float4* p = tgt + (size_t)batch * (NPB / 4) + (size_t)sub * F4;
    float mn = 3.4e38f, mx = -3.4e38f;
    #pragma unroll
    for (int i = 0; i < F4 / 256; ++i) {       // 4 iterations
        float4 v = p[i * 256 + threadIdx.x];
        mn = fminf(mn, fminf(fminf(v.x, v.y), fminf(v.z, v.w)));
        mx = fmaxf(mx, fmaxf(fmaxf(v.x, v.y), fmaxf(v.z, v.w)));
    }
    #pragma unroll
    for (int o = 1; o < 64; o <<= 1) {
        mn = fminf(mn, __shfl_xor(mn, o));
        mx = fmaxf(mx, __shfl_xor(mx, o));
    }
    __shared__ float smn[4], smx[4];
    const int wave = threadIdx.x >> 6, lane = threadIdx.x & 63;
    if (lane == 0) { smn[wave] = mn; smx[wave] = mx; }
    __syncthreads();
    if (threadIdx.x == 0) {
        mmn[blockIdx.x] = fminf(fminf(smn[0], smn[1]), fminf(smn[2], smn[3]));
        mmx[blockIdx.x] = fmaxf(fmaxf(smx[0], smx[1]), fmaxf(smx[2], smx[3]));
    }
}

// ---------- per-point scatter of 16 bins around the point's own bin ----------
// u = x*s64 + b0 puts bin centers at integer u. ibin = rint(clamp(u)),
// d = uc - ibin in [-0.5,0.5]. E(ibin+j) = A * r^j * C_j with A = e^{-d^2/2},
// r = e^d, C_j = e^{-j^2/2} literals. Window j in [-8,7] -> rows ibin+7..ibin+22.
// Clamp to [-7.49, 71.49] keeps ibin in [-7,71] -> rows 0..93; clamped points
// write only guard rows (weight reaching a real bin <= e^-28).
__device__ __forceinline__ void point16(float xin, float s64, float b0,
                                        float* __restrict__ hls) {
    const float C1 = 0.60653065971f,    C2 = 0.13533528324f,
                C3 = 0.01110899654f,    C4 = 3.35462627903e-4f,
                C5 = 3.72665317208e-6f, C6 = 1.52299797447e-8f,
                C7 = 2.28973484833e-11f, C8 = 1.26641655490e-14f;
    float u  = fmaf(xin, s64, b0);
    float uc = __builtin_amdgcn_fmed3f(u, -7.49f, 71.49f);
    float fb = rintf(uc);
    float d  = uc - fb;
    float* hb = hls + (((int)fb + 7) << 6);   // row ibin-8+15, this lane's column
    float x  = d * L2E;
    float r  = __builtin_amdgcn_exp2f(x);
    float ri = __builtin_amdgcn_exp2f(-x);
    float t  = d * QF;
    float A  = __builtin_amdgcn_exp2f(-(t * t));
    atomicAdd(hb + 8 * 64, A);                // center bin, j=0
    float T = A, U = A;
    T *= r;  atomicAdd(hb + 9 * 64,  T * C1);
    T *= r;  atomicAdd(hb + 10 * 64, T * C2);
    T *= r;  atomicAdd(hb + 11 * 64, T * C3);
    T *= r;  atomicAdd(hb + 12 * 64, T * C4);
    T *= r;  atomicAdd(hb + 13 * 64, T * C5);
    T *= r;  atomicAdd(hb + 14 * 64, T * C6);
    T *= r;  atomicAdd(hb + 15 * 64, T * C7);
    U *= ri; atomicAdd(hb + 7 * 64,  U * C1);
    U *= ri; atomicAdd(hb + 6 * 64,  U * C2);
    U *= ri; atomicAdd(hb + 5 * 64,  U * C3);
    U *= ri; atomicAdd(hb + 4 * 64,  U * C4);
    U *= ri; atomicAdd(hb + 3 * 64,  U * C5);
    U *= ri; atomicAdd(hb + 2 * 64,  U * C6);
    U *= ri; atomicAdd(hb + 1 * 64,  U * C7);
    U *= ri; atomicAdd(hb + 0,       U * C8);
}

// ---------- pass 2: scatter histogram, one visit per point ----------
__global__ __launch_bounds__(256) void hist_k(const float4* __restrict__ pred,
                                              const float4* __restrict__ tgt,
                                              const float* __restrict__ mmn,
                                              const float* __restrict__ mmx,
                                              float* __restrict__ hist) {
    __shared__ float hl[GROWS * 64];
    const int blk   = blockIdx.x;
    const int tens  = blk & 1;
    const int batch = (blk >> 1) & (NB - 1);
    const int chunk = blk >> 5;                      // 0..CB-1
    const int tid   = threadIdx.x;
    const int lane  = tid & 63;
    const int q     = tid >> 6;                      // wave index

    // zero LDS histogram (1536 float4)
    float4* z = (float4*)hl;
    #pragma unroll
    for (int i = 0; i < 6; ++i) z[i * 256 + tid] = make_float4(0.f, 0.f, 0.f, 0.f);

    const int F4C = NPB / 4 / CB;                    // 1024 float4 per chunk
    const float4* __restrict__ src = (tens ? tgt : pred)
        + (size_t)batch * (NPB / 4) + (size_t)chunk * F4C;

    // issue first data load before the prologue reduction (overlap)
    float4 v = src[tid];

    // lane-parallel reduce of this batch's 64 minmax partials
    float vmin = mmn[batch * MMB + lane];
    float vmax = mmx[batch * MMB + lane];
    #pragma unroll
    for (int o = 1; o < 64; o <<= 1) {
        vmin = fminf(vmin, __shfl_xor(vmin, o));
        vmax = fmaxf(vmax, __shfl_xor(vmax, o));
    }
    const float s64 = 64.0f / (vmax - vmin + EPSF);
    const float b0  = fmaf(-vmin, s64, -0.5f);       // u = x*s64 + b0

    float* hls = hl + lane;                          // this lane's column

    __syncthreads();                                 // LDS zero visible

    #pragma unroll 1
    for (int it = 0; it < 4; ++it) {                 // 4 float4 per thread
        float4 vn = src[(it < 3 ? (it + 1) * 256 : 0) + tid];
        point16(v.x, s64, b0, hls);
        point16(v.y, s64, b0, hls);
        point16(v.z, s64, b0, hls);
        point16(v.w, s64, b0, hls);
        v = vn;
    }
    __syncthreads();                                 // all scatters done

    // reduce real bins (rows 15..78) over 64 columns; thread (q,bin) sums
    // 16 columns on a rotated diagonal (bank = col%32, 2-way, conflict-free)
    const int bin  = lane;
    const int brow = (bin + 15) << 6;
    float part = 0.f;
    #pragma unroll
    for (int i = 0; i < 16; ++i) {
        int col = (bin + (q << 4) + i) & 63;
        part += hl[brow + col];
    }
    // stage quarter-partials in rows 0..3 (disjoint from rows 15..78 reads)
    hl[q * 64 + bin] = part;
    __syncthreads();
    if (tid < 64) {
        float s = hl[bin] + hl[64 + bin] + hl[128 + bin] + hl[192 + bin];
        unsafeAtomicAdd(&hist[(tens * NB + batch) * NBINS + bin], s);
    }
}

// ---------- pass 3: KL (fp32, v_log), tiny ----------
__global__ __launch_bounds__(256) void final_k(const float* __restrict__ hist,
                                               float* __restrict__ out) {
    const int lane = threadIdx.x & 63, wave = threadIdx.x >> 6;
    __shared__ float wacc[4];
    float a = 0.0f;
    for (int b = wave; b < NB; b += 4) {
        float hp = hist[b * NBINS + lane];
        float ht = hist[(NB + b) * NBINS + lane];
        float sp = hp, st = ht;
        #pragma unroll
        for (int o = 1; o < 64; o <<= 1) {
            sp += __shfl_xor(sp, o);
            st += __shfl_xor(st, o);
        }
        float pp = hp / (sp + EPSF);
        float pt = ht / (st + EPSF);
        float term = pt * ((__builtin_amdgcn_logf(pt + EPSF)
                          - __builtin_amdgcn_logf(pp + EPSF)) * LN2);
        #pragma unroll
        for (int o = 1; o < 64; o <<= 1) term += __shfl_xor(term, o);
        a += term;
    }
    if (lane == 0) wacc[wave] = a;
    __syncthreads();
    if (threadIdx.x == 0)
        out[0] = 0.1f * (wacc[0] + wacc[1] + wacc[2] + wacc[3]) / (float)NB;
}

extern "C" void kernel_launch(void* const* d_in, const int* in_sizes, int n_in,
                              void* d_out, int out_size, void* d_ws, size_t ws_size,
                              hipStream_t stream) {
    const float* pred = (const float*)d_in[0];
    const float* tgt  = (const float*)d_in[1];
    float* mmn  = (float*)d_ws;
    float* mmx  = mmn + NB * MMB;
    float* hist = mmx + NB * MMB;
    float* out  = (float*)d_out;

    minmax_k<<<NB * MMB, 256, 0, stream>>>((const float4*)tgt, mmn, mmx, hist);
    hist_k  <<<2 * NB * CB, 256, 0, stream>>>((const float4*)pred, (const float4*)tgt,
                                              mmn, mmx, hist);
    final_k <<<1, 256, 0, stream>>>(hist, out);
}

// Round 3
// 106.355 us; speedup vs baseline: 6.9949x; 6.9949x over previous
//
#include <hip/hip_runtime.h>
#include <math.h>

// Problem constants
#define NB    16            // batches
#define NPB   (512*512)     // elements per batch
#define NBINS 64
#define MMB   64            // minmax blocks per batch (grid 1024 = 4/CU)
#define CB    64            // hist chunks per (tensor,batch) -> grid 2*16*64 = 2048
#define EPSF  1e-8f
#define QF    0.84932180517f   // sqrt(0.5*log2(e)); exp(-d^2/2) = exp2(-(q*d)^2)
#define L2E   1.44269504089f   // log2(e)
#define LN2   0.69314718056f
#define K16   1.12535175e-7f   // e^-16 (anchor-2 rate adjust)
#define K16I  8886110.5f       // e^+16

// R20: revert to R17 dense structure (R18/R19 LDS-scatter was 15x WORSE:
// 673 us, VALUBusy 1.7% -- DS pipe is ~3 cyc/instr per CU, 16 ds_add/point
// >> dense VALU cost; scatter abandoned). New lever: VOP3P packed fp32.
// The two anchor recurrence chains pair exactly: (T,S)*=(r,r2) and
// (U,V)*=(ri,ri2) as float2 -> v_pk_mul_f32 + v_pk_fma_f32, 31 packed ops
// for all 32 bins instead of 62 scalar. Arithmetic is bit-identical to R17
// (same products, same FMA order per bin). acc2[k] = (bin kwb+k, bin kwb+k+16).

typedef float v2f __attribute__((ext_vector_type(2)));

// ws layout: mmn[1024] | mmx[1024] | hist[2][16][64]

// ---------- pass 1: per-batch block-level min/max (also zeroes hist) ----------
__global__ __launch_bounds__(256) void minmax_k(const float4* __restrict__ tgt,
                                                float* __restrict__ mmn,
                                                float* __restrict__ mmx,
                                                float* __restrict__ hist) {
    const int batch = blockIdx.x / MMB, sub = blockIdx.x % MMB;
    if (sub == 0 && threadIdx.x < 128) {
        const int tens = threadIdx.x >> 6, lane = threadIdx.x & 63;
        hist[(tens * NB + batch) * NBINS + lane] = 0.0f;
    }

    const int F4 = NPB / 4 / MMB;              // 1024 float4 per block
    const float4* p = tgt + (size_t)batch * (NPB / 4) + (size_t)sub * F4;
    float mn = 3.4e38f, mx = -3.4e38f;
    #pragma unroll
    for (int i = 0; i < F4 / 256; ++i) {       // 4 iterations
        float4 v = p[i * 256 + threadIdx.x];
        mn = fminf(mn, fminf(fminf(v.x, v.y), fminf(v.z, v.w)));
        mx = fmaxf(mx, fmaxf(fmaxf(v.x, v.y), fmaxf(v.z, v.w)));
    }
    #pragma unroll
    for (int o = 1; o < 64; o <<= 1) {
        mn = fminf(mn, __shfl_xor(mn, o));
        mx = fmaxf(mx, __shfl_xor(mx, o));
    }
    __shared__ float smn[4], smx[4];
    const int wave = threadIdx.x >> 6, lane = threadIdx.x & 63;
    if (lane == 0) { smn[wave] = mn; smx[wave] = mx; }
    __syncthreads();
    if (threadIdx.x == 0) {
        mmn[blockIdx.x] = fminf(fminf(smn[0], smn[1]), fminf(smn[2], smn[3]));
        mmx[blockIdx.x] = fmaxf(fmaxf(smx[0], smx[1]), fmaxf(smx[2], smx[3]));
    }
}

// ---------- per-point update of 32 bins, packed-fp32 dual anchors ----------
// d = u - (kwbase+8): anchor1 at bin kwbase+8 (bins 0..15 of the wave's 32),
// anchor2 at kwbase+24 (bins 16..31). E(m+i) = A * rho^i * C_i with
// C_i = e^{-i^2/2} folded into the fma. Packed: x-half = anchor1 chain,
// y-half = anchor2 chain (rate r*K16 / ri*K16I). d clamped to [-30,46]:
// outside, both A==0 before any rho power can overflow, so far points
// contribute exactly 0 (true contribution < e^-19). acc2[k] = bins (k, k+16).
__device__ __forceinline__ void point32(float xin, float s64, float bk8,
                                        v2f* __restrict__ acc2) {
    const float C1 = 0.60653065971f,    C2 = 0.13533528324f,
                C3 = 0.01110899654f,    C4 = 3.35462627903e-4f,
                C5 = 3.72665317208e-6f, C6 = 1.52299797447e-8f,
                C7 = 2.28973484833e-11f, C8 = 1.26641655490e-14f;
    const v2f c1 = {C1, C1}, c2 = {C2, C2}, c3 = {C3, C3}, c4 = {C4, C4},
              c5 = {C5, C5}, c6 = {C6, C6}, c7 = {C7, C7}, c8 = {C8, C8};
    float d   = fmaf(xin, s64, bk8);
    float dc  = __builtin_amdgcn_fmed3f(d, -30.0f, 46.0f);
    float x   = dc * L2E;
    float r   = __builtin_amdgcn_exp2f(x);
    float ri  = __builtin_amdgcn_exp2f(-x);
    float t1  = dc * QF;
    float A1  = __builtin_amdgcn_exp2f(-(t1 * t1));
    float t2  = fmaf(dc, QF, -16.0f * QF);
    float A2  = __builtin_amdgcn_exp2f(-(t2 * t2));
    v2f RR = {r,  r  * K16};
    v2f RI = {ri, ri * K16I};
    v2f TS = {A1, A2};
    v2f UV = TS;
    acc2[8] += TS;                                             // bins (8, 24)
    TS *= RR; acc2[9]  = __builtin_elementwise_fma(TS, c1, acc2[9]);
    TS *= RR; acc2[10] = __builtin_elementwise_fma(TS, c2, acc2[10]);
    TS *= RR; acc2[11] = __builtin_elementwise_fma(TS, c3, acc2[11]);
    TS *= RR; acc2[12] = __builtin_elementwise_fma(TS, c4, acc2[12]);
    TS *= RR; acc2[13] = __builtin_elementwise_fma(TS, c5, acc2[13]);
    TS *= RR; acc2[14] = __builtin_elementwise_fma(TS, c6, acc2[14]);
    TS *= RR; acc2[15] = __builtin_elementwise_fma(TS, c7, acc2[15]);
    UV *= RI; acc2[7]  = __builtin_elementwise_fma(UV, c1, acc2[7]);
    UV *= RI; acc2[6]  = __builtin_elementwise_fma(UV, c2, acc2[6]);
    UV *= RI; acc2[5]  = __builtin_elementwise_fma(UV, c3, acc2[5]);
    UV *= RI; acc2[4]  = __builtin_elementwise_fma(UV, c4, acc2[4]);
    UV *= RI; acc2[3]  = __builtin_elementwise_fma(UV, c5, acc2[3]);
    UV *= RI; acc2[2]  = __builtin_elementwise_fma(UV, c6, acc2[2]);
    UV *= RI; acc2[1]  = __builtin_elementwise_fma(UV, c7, acc2[1]);
    UV *= RI; acc2[0]  = __builtin_elementwise_fma(UV, c8, acc2[0]);
}

// ---------- pass 2: gather histogram, 32 bins/wave, wave-pairs split chunk ----
// Waves {0,1} cover bins {0-31, 32-63} on the chunk's first half; waves {2,3}
// the second half -> each point processed 2x. 1-deep load prefetch (R9).
__global__ __launch_bounds__(256, 4) void hist_k(const float4* __restrict__ pred,
                                                 const float4* __restrict__ tgt,
                                                 const float* __restrict__ mmn,
                                                 const float* __restrict__ mmx,
                                                 float* __restrict__ hist) {
    const int blk   = blockIdx.x;
    const int tens  = blk & 1;
    const int batch = (blk >> 1) & (NB - 1);
    const int chunk = blk >> 5;                      // 0..CB-1
    const int wave  = threadIdx.x >> 6, lane = threadIdx.x & 63;
    const int kwb   = 32 * (wave & 1);               // this wave's first bin
    const int pair  = wave >> 1;                     // which half-chunk

    const int F4C = NPB / 4 / CB;                    // 1024 float4 per chunk
    const int F4H = F4C / 2;                         // 512 per half
    const float4* __restrict__ src = (tens ? tgt : pred)
        + (size_t)batch * (NPB / 4) + (size_t)chunk * F4C + (size_t)pair * F4H;

    // issue first data load before the prologue reduction (overlap)
    float4 v = src[lane];

    // lane-parallel reduce of this batch's 64 minmax partials
    float vmin = mmn[batch * MMB + lane];
    float vmax = mmx[batch * MMB + lane];
    #pragma unroll
    for (int o = 1; o < 64; o <<= 1) {
        vmin = fminf(vmin, __shfl_xor(vmin, o));
        vmax = fmaxf(vmax, __shfl_xor(vmax, o));
    }
    const float s64 = 64.0f / (vmax - vmin + EPSF);
    // d = u - (kwb+8) = x*s64 + bk8
    const float bk8 = fmaf(-vmin, s64, -0.5f) - (float)(kwb + 8);

    v2f acc2[16];
    #pragma unroll
    for (int k = 0; k < 16; ++k) acc2[k] = (v2f){0.0f, 0.0f};

    const int NIT = F4H / 64;                        // 8 wave-iterations
    #pragma unroll 1
    for (int it = 0; it < NIT; ++it) {
        // prefetch next iteration's data; latency hides under the burst
        float4 vn = src[(it < NIT - 1 ? (it + 1) * 64 : 0) + lane];
        point32(v.x, s64, bk8, acc2);
        point32(v.y, s64, bk8, acc2);
        point32(v.z, s64, bk8, acc2);
        point32(v.w, s64, bk8, acc2);
        v = vn;
    }

    // in-wave reduce: 32 butterflies; lane i keeps bin kwb+i
    // acc2[k] = (bin kwb+k, bin kwb+k+16)
    float keep = 0.0f;
    #pragma unroll
    for (int i = 0; i < 16; ++i) {
        float tx = acc2[i].x;
        #pragma unroll
        for (int o = 1; o < 64; o <<= 1) tx += __shfl_xor(tx, o);
        if (lane == i) keep = tx;
        float ty = acc2[i].y;
        #pragma unroll
        for (int o = 1; o < 64; o <<= 1) ty += __shfl_xor(ty, o);
        if (lane == i + 16) keep = ty;
    }
    if (lane < 32)
        unsafeAtomicAdd(&hist[(tens * NB + batch) * NBINS + kwb + lane], keep);
}

// ---------- pass 3: KL (fp32, v_log), tiny ----------
__global__ __launch_bounds__(256) void final_k(const float* __restrict__ hist,
                                               float* __restrict__ out) {
    const int lane = threadIdx.x & 63, wave = threadIdx.x >> 6;
    __shared__ float wacc[4];
    float a = 0.0f;
    for (int b = wave; b < NB; b += 4) {
        float hp = hist[b * NBINS + lane];
        float ht = hist[(NB + b) * NBINS + lane];
        float sp = hp, st = ht;
        #pragma unroll
        for (int o = 1; o < 64; o <<= 1) {
            sp += __shfl_xor(sp, o);
            st += __shfl_xor(st, o);
        }
        float pp = hp / (sp + EPSF);
        float pt = ht / (st + EPSF);
        float term = pt * ((__builtin_amdgcn_logf(pt + EPSF)
                          - __builtin_amdgcn_logf(pp + EPSF)) * LN2);
        #pragma unroll
        for (int o = 1; o < 64; o <<= 1) term += __shfl_xor(term, o);
        a += term;
    }
    if (lane == 0) wacc[wave] = a;
    __syncthreads();
    if (threadIdx.x == 0)
        out[0] = 0.1f * (wacc[0] + wacc[1] + wacc[2] + wacc[3]) / (float)NB;
}

extern "C" void kernel_launch(void* const* d_in, const int* in_sizes, int n_in,
                              void* d_out, int out_size, void* d_ws, size_t ws_size,
                              hipStream_t stream) {
    const float* pred = (const float*)d_in[0];
    const float* tgt  = (const float*)d_in[1];
    float* mmn  = (float*)d_ws;
    float* mmx  = mmn + NB * MMB;
    float* hist = mmx + NB * MMB;
    float* out  = (float*)d_out;

    minmax_k<<<NB * MMB, 256, 0, stream>>>((const float4*)tgt, mmn, mmx, hist);
    hist_k  <<<2 * NB * CB, 256, 0, stream>>>((const float4*)pred, (const float4*)tgt,
                                              mmn, mmx, hist);
    final_k <<<1, 256, 0, stream>>>(hist, out);
}

// Round 5
// 103.210 us; speedup vs baseline: 7.2080x; 1.0305x over previous
//
#include <hip/hip_runtime.h>
#include <math.h>

// Problem constants
#define NB    16            // batches
#define NPB   (512*512)     // elements per batch
#define NBINS 64
#define MMB   64            // minmax blocks per batch (grid 1024 = 4/CU)
#define CB    64            // hist chunks per (tensor,batch) -> grid 2*16*64 = 2048
#define EPSF  1e-8f
#define QF    0.84932180517f   // sqrt(0.5*log2(e)); exp(-d^2/2) = exp2(-(q*d)^2)
#define L2E   1.44269504089f   // log2(e)
#define LN2   0.69314718056f
#define K16   1.12535175e-7f   // e^-16 (anchor-2 rate adjust)
#define K16I  8886110.5f       // e^+16

// R22 = R21 with the exchange-reduce FIXED. R21 bug: exchanged vk (the value
// this lane KEEPS) -> summed lo(l)+hi(l^1), mixing bins (absmax 3e-6). Fix:
// send vo (the value the partner keeps), keep vk: val = vk + shfl_xor(vo,o).
// Partner's vo IS this lane's bin -> correct pairing; lane-bit order 0,1,2..
// reproduces the old per-bin butterfly's summation tree exactly -> absmax 0.
// R20 history: packed-fp32 chains (106.4 us total, hist ~38 us).
// Known fixed costs in the timed path: ~43 us harness 268MB ws re-poison
// (fillBufferAligned, not controllable), minmax ~6-8, final ~4, gaps ~10.

typedef float v2f __attribute__((ext_vector_type(2)));

// ws layout: mmn[1024] | mmx[1024] | hist[2][16][64]

// ---------- pass 1: per-batch block-level min/max (also zeroes hist) ----------
__global__ __launch_bounds__(256) void minmax_k(const float4* __restrict__ tgt,
                                                float* __restrict__ mmn,
                                                float* __restrict__ mmx,
                                                float* __restrict__ hist) {
    const int batch = blockIdx.x / MMB, sub = blockIdx.x % MMB;
    if (sub == 0 && threadIdx.x < 128) {
        const int tens = threadIdx.x >> 6, lane = threadIdx.x & 63;
        hist[(tens * NB + batch) * NBINS + lane] = 0.0f;
    }

    const int F4 = NPB / 4 / MMB;              // 1024 float4 per block
    const float4* p = tgt + (size_t)batch * (NPB / 4) + (size_t)sub * F4;
    float mn = 3.4e38f, mx = -3.4e38f;
    #pragma unroll
    for (int i = 0; i < F4 / 256; ++i) {       // 4 iterations
        float4 v = p[i * 256 + threadIdx.x];
        mn = fminf(mn, fminf(fminf(v.x, v.y), fminf(v.z, v.w)));
        mx = fmaxf(mx, fmaxf(fmaxf(v.x, v.y), fmaxf(v.z, v.w)));
    }
    #pragma unroll
    for (int o = 1; o < 64; o <<= 1) {
        mn = fminf(mn, __shfl_xor(mn, o));
        mx = fmaxf(mx, __shfl_xor(mx, o));
    }
    __shared__ float smn[4], smx[4];
    const int wave = threadIdx.x >> 6, lane = threadIdx.x & 63;
    if (lane == 0) { smn[wave] = mn; smx[wave] = mx; }
    __syncthreads();
    if (threadIdx.x == 0) {
        mmn[blockIdx.x] = fminf(fminf(smn[0], smn[1]), fminf(smn[2], smn[3]));
        mmx[blockIdx.x] = fmaxf(fmaxf(smx[0], smx[1]), fmaxf(smx[2], smx[3]));
    }
}

// ---------- per-point update of 32 bins, packed-fp32 dual anchors ----------
// d = u - (kwbase+8): anchor1 at bin kwbase+8 (bins 0..15 of the wave's 32),
// anchor2 at kwbase+24 (bins 16..31). E(m+i) = A * rho^i * C_i with
// C_i = e^{-i^2/2} folded into the fma. Packed: x-half = anchor1 chain,
// y-half = anchor2 chain (rate r*K16 / ri*K16I). d clamped to [-30,46]:
// outside, both A==0 before any rho power can overflow, so far points
// contribute exactly 0 (true contribution < e^-19). acc2[k] = bins (k, k+16).
__device__ __forceinline__ void point32(float xin, float s64, float bk8,
                                        v2f* __restrict__ acc2) {
    const float C1 = 0.60653065971f,    C2 = 0.13533528324f,
                C3 = 0.01110899654f,    C4 = 3.35462627903e-4f,
                C5 = 3.72665317208e-6f, C6 = 1.52299797447e-8f,
                C7 = 2.28973484833e-11f, C8 = 1.26641655490e-14f;
    const v2f c1 = {C1, C1}, c2 = {C2, C2}, c3 = {C3, C3}, c4 = {C4, C4},
              c5 = {C5, C5}, c6 = {C6, C6}, c7 = {C7, C7}, c8 = {C8, C8};
    float d   = fmaf(xin, s64, bk8);
    float dc  = __builtin_amdgcn_fmed3f(d, -30.0f, 46.0f);
    float x   = dc * L2E;
    float r   = __builtin_amdgcn_exp2f(x);
    float ri  = __builtin_amdgcn_exp2f(-x);
    float t1  = dc * QF;
    float A1  = __builtin_amdgcn_exp2f(-(t1 * t1));
    float t2  = fmaf(dc, QF, -16.0f * QF);
    float A2  = __builtin_amdgcn_exp2f(-(t2 * t2));
    v2f RR = {r,  r  * K16};
    v2f RI = {ri, ri * K16I};
    v2f TS = {A1, A2};
    v2f UV = TS;
    acc2[8] += TS;                                             // bins (8, 24)
    TS *= RR; acc2[9]  = __builtin_elementwise_fma(TS, c1, acc2[9]);
    TS *= RR; acc2[10] = __builtin_elementwise_fma(TS, c2, acc2[10]);
    TS *= RR; acc2[11] = __builtin_elementwise_fma(TS, c3, acc2[11]);
    TS *= RR; acc2[12] = __builtin_elementwise_fma(TS, c4, acc2[12]);
    TS *= RR; acc2[13] = __builtin_elementwise_fma(TS, c5, acc2[13]);
    TS *= RR; acc2[14] = __builtin_elementwise_fma(TS, c6, acc2[14]);
    TS *= RR; acc2[15] = __builtin_elementwise_fma(TS, c7, acc2[15]);
    UV *= RI; acc2[7]  = __builtin_elementwise_fma(UV, c1, acc2[7]);
    UV *= RI; acc2[6]  = __builtin_elementwise_fma(UV, c2, acc2[6]);
    UV *= RI; acc2[5]  = __builtin_elementwise_fma(UV, c3, acc2[5]);
    UV *= RI; acc2[4]  = __builtin_elementwise_fma(UV, c4, acc2[4]);
    UV *= RI; acc2[3]  = __builtin_elementwise_fma(UV, c5, acc2[3]);
    UV *= RI; acc2[2]  = __builtin_elementwise_fma(UV, c6, acc2[2]);
    UV *= RI; acc2[1]  = __builtin_elementwise_fma(UV, c7, acc2[1]);
    UV *= RI; acc2[0]  = __builtin_elementwise_fma(UV, c8, acc2[0]);
}

// ---------- pass 2: gather histogram, 32 bins/wave, wave-pairs split chunk ----
// Waves {0,1} cover bins {0-31, 32-63} on the chunk's first half; waves {2,3}
// the second half -> each point processed 2x. 1-deep load prefetch (R9).
__global__ __launch_bounds__(256, 4) void hist_k(const float4* __restrict__ pred,
                                                 const float4* __restrict__ tgt,
                                                 const float* __restrict__ mmn,
                                                 const float* __restrict__ mmx,
                                                 float* __restrict__ hist) {
    const int blk   = blockIdx.x;
    const int tens  = blk & 1;
    const int batch = (blk >> 1) & (NB - 1);
    const int chunk = blk >> 5;                      // 0..CB-1
    const int wave  = threadIdx.x >> 6, lane = threadIdx.x & 63;
    const int kwb   = 32 * (wave & 1);               // this wave's first bin
    const int pair  = wave >> 1;                     // which half-chunk

    const int F4C = NPB / 4 / CB;                    // 1024 float4 per chunk
    const int F4H = F4C / 2;                         // 512 per half
    const float4* __restrict__ src = (tens ? tgt : pred)
        + (size_t)batch * (NPB / 4) + (size_t)chunk * F4C + (size_t)pair * F4H;

    // issue first data load before the prologue reduction (overlap)
    float4 v = src[lane];

    // lane-parallel reduce of this batch's 64 minmax partials
    float vmin = mmn[batch * MMB + lane];
    float vmax = mmx[batch * MMB + lane];
    #pragma unroll
    for (int o = 1; o < 64; o <<= 1) {
        vmin = fminf(vmin, __shfl_xor(vmin, o));
        vmax = fmaxf(vmax, __shfl_xor(vmax, o));
    }
    const float s64 = 64.0f / (vmax - vmin + EPSF);
    // d = u - (kwb+8) = x*s64 + bk8
    const float bk8 = fmaf(-vmin, s64, -0.5f) - (float)(kwb + 8);

    v2f acc2[16];
    #pragma unroll
    for (int k = 0; k < 16; ++k) acc2[k] = (v2f){0.0f, 0.0f};

    const int NIT = F4H / 64;                        // 8 wave-iterations
    #pragma unroll 1
    for (int it = 0; it < NIT; ++it) {
        // prefetch next iteration's data; latency hides under the burst
        float4 vn = src[(it < NIT - 1 ? (it + 1) * 64 : 0) + lane];
        point32(v.x, s64, bk8, acc2);
        point32(v.y, s64, bk8, acc2);
        point32(v.z, s64, bk8, acc2);
        point32(v.w, s64, bk8, acc2);
        v = vn;
    }

    // tree-exchange reduce: absorb bin-index bit s into lane bit s.
    // Each lane KEEPS vk (the bin whose bit s matches its own lane bit s)
    // and SENDS vo (the bin the partner keeps). Partner's vo is this lane's
    // bin with the partner's partial -> val[p] = vk + shfl_xor(vo, o).
    // Invariant after step s: val[i] = partial of bin kwb + ((i << (s+1)) |
    // (lane & (2^(s+1)-1))) summed over lanes differing in bits 0..s.
    // Lane-bit order 0,1,2,.. == old per-bin butterfly tree -> bit-exact.
    float val[32];
    #pragma unroll
    for (int k = 0; k < 16; ++k) { val[k] = acc2[k].x; val[16 + k] = acc2[k].y; }
    #pragma unroll
    for (int s = 0; s < 5; ++s) {
        const int o = 1 << s;
        const bool b = (lane >> s) & 1;
        #pragma unroll
        for (int p = 0; p < (16 >> s); ++p) {
            float lo = val[2 * p], hi = val[2 * p + 1];
            float vk = b ? hi : lo;          // bin this lane keeps
            float vo = b ? lo : hi;          // bin the partner keeps
            val[p] = vk + __shfl_xor(vo, o);
        }
    }
    float tot = val[0] + __shfl_xor(val[0], 32);     // bin kwb + (lane & 31)
    if (lane < 32)
        unsafeAtomicAdd(&hist[(tens * NB + batch) * NBINS + kwb + lane], tot);
}

// ---------- pass 3: KL (fp32, v_log), tiny ----------
__global__ __launch_bounds__(256) void final_k(const float* __restrict__ hist,
                                               float* __restrict__ out) {
    const int lane = threadIdx.x & 63, wave = threadIdx.x >> 6;
    __shared__ float wacc[4];
    float a = 0.0f;
    for (int b = wave; b < NB; b += 4) {
        float hp = hist[b * NBINS + lane];
        float ht = hist[(NB + b) * NBINS + lane];
        float sp = hp, st = ht;
        #pragma unroll
        for (int o = 1; o < 64; o <<= 1) {
            sp += __shfl_xor(sp, o);
            st += __shfl_xor(st, o);
        }
        float pp = hp / (sp + EPSF);
        float pt = ht / (st + EPSF);
        float term = pt * ((__builtin_amdgcn_logf(pt + EPSF)
                          - __builtin_amdgcn_logf(pp + EPSF)) * LN2);
        #pragma unroll
        for (int o = 1; o < 64; o <<= 1) term += __shfl_xor(term, o);
        a += term;
    }
    if (lane == 0) wacc[wave] = a;
    __syncthreads();
    if (threadIdx.x == 0)
        out[0] = 0.1f * (wacc[0] + wacc[1] + wacc[2] + wacc[3]) / (float)NB;
}

extern "C" void kernel_launch(void* const* d_in, const int* in_sizes, int n_in,
                              void* d_out, int out_size, void* d_ws, size_t ws_size,
                              hipStream_t stream) {
    const float* pred = (const float*)d_in[0];
    const float* tgt  = (const float*)d_in[1];
    float* mmn  = (float*)d_ws;
    float* mmx  = mmn + NB * MMB;
    float* hist = mmx + NB * MMB;
    float* out  = (float*)d_out;

    minmax_k<<<NB * MMB, 256, 0, stream>>>((const float4*)tgt, mmn, mmx, hist);
    hist_k  <<<2 * NB * CB, 256, 0, stream>>>((const float4*)pred, (const float4*)tgt,
                                              mmn, mmx, hist);
    final_k <<<1, 256, 0, stream>>>(hist, out);
}

// Round 8
// 102.795 us; speedup vs baseline: 7.2372x; 1.0040x over previous
//
#include <hip/hip_runtime.h>
#include <math.h>

// Problem constants
#define NB    16            // batches
#define NPB   (512*512)     // elements per batch
#define NBINS 64
#define MMB   64            // minmax blocks per batch (grid 1024 = 4/CU)
#define CB    64            // hist chunks per (tensor,batch) -> grid 2*16*64 = 2048
#define EPSF  1e-8f
#define QF    0.84932180517f   // sqrt(0.5*log2(e)); exp(-d^2/2) = exp2(-(q*d)^2)
#define L2E   1.44269504089f   // log2(e)
#define LN2   0.69314718056f
#define K16   1.12535175e-7f   // e^-16
#define K16I  8886110.5f       // e^+16
#define K32   1.26641655e-14f  // e^-32
#define K32I  7.8962960e13f    // e^+32
#define K48   1.42516408e-21f  // e^-48
#define K48I  7.01673591e20f   // e^+48

// R25: 3-kernel revert (cooperative fusion R23/R24 never launched: bit-
// identical error 6.318e-6 == |ref| with out=0 -> hipLaunchCooperativeKernel
// silently rejected under graph capture; fusion abandoned) + single-visit
// 64-bin hist waves. R22 visited each point TWICE (2 waves x 32 bins);
// now 4 anchors (bins 8/24/40/56, rates r*e^{0,-16,-32,-48}) give all 64
// bins in one visit: packed chain ops conserved (62/point), but setup
// halves (exp2 8->6/point), global loads halve, each wave does a quarter
// chunk (NIT=4). Clamp widened to [-30,78]: single d=u-8 must stay valid
// for all 64 bins; at bounds max rate e^78=7.4e33 finite, A's underflow
// to 0, clamp only bites where true contribution <= e^-242. Epilogue =
// 6-step exchange tree (64 bins absorb all 6 lane bits), 64 atomics/wave.

typedef float v2f __attribute__((ext_vector_type(2)));

// ws layout: mmn[1024] | mmx[1024] | hist[2][16][64]

// ---------- pass 1: per-batch block-level min/max (also zeroes hist) ----------
__global__ __launch_bounds__(256) void minmax_k(const float4* __restrict__ tgt,
                                                float* __restrict__ mmn,
                                                float* __restrict__ mmx,
                                                float* __restrict__ hist) {
    const int batch = blockIdx.x / MMB, sub = blockIdx.x % MMB;
    if (sub == 0 && threadIdx.x < 128) {
        const int tens = threadIdx.x >> 6, lane = threadIdx.x & 63;
        hist[(tens * NB + batch) * NBINS + lane] = 0.0f;
    }

    const int F4 = NPB / 4 / MMB;              // 1024 float4 per block
    const float4* p = tgt + (size_t)batch * (NPB / 4) + (size_t)sub * F4;
    float mn = 3.4e38f, mx = -3.4e38f;
    #pragma unroll
    for (int i = 0; i < F4 / 256; ++i) {       // 4 iterations
        float4 v = p[i * 256 + threadIdx.x];
        mn = fminf(mn, fminf(fminf(v.x, v.y), fminf(v.z, v.w)));
        mx = fmaxf(mx, fmaxf(fmaxf(v.x, v.y), fmaxf(v.z, v.w)));
    }
    #pragma unroll
    for (int o = 1; o < 64; o <<= 1) {
        mn = fminf(mn, __shfl_xor(mn, o));
        mx = fmaxf(mx, __shfl_xor(mx, o));
    }
    __shared__ float smn[4], smx[4];
    const int wave = threadIdx.x >> 6, lane = threadIdx.x & 63;
    if (lane == 0) { smn[wave] = mn; smx[wave] = mx; }
    __syncthreads();
    if (threadIdx.x == 0) {
        mmn[blockIdx.x] = fminf(fminf(smn[0], smn[1]), fminf(smn[2], smn[3]));
        mmx[blockIdx.x] = fmaxf(fmaxf(smx[0], smx[1]), fmaxf(smx[2], smx[3]));
    }
}

// ---------- per-point update of ALL 64 bins, 4 packed anchors ----------
// d = u - 8. Anchor m in {8,24,40,56} covers bins m-8..m+7:
// E(m+i) = A_m * rho_m^i * C_i, A_m = e^{-(d-(m-8))^2/2}, rho_m = e^d * e^{-(m-8)}.
// Packed pairs: A-array x/y = anchors (8,24); B-array x/y = anchors (40,56).
// accA[k] = bins (k, 16+k); accB[k] = bins (32+k, 48+k), k = 0..15.
__device__ __forceinline__ void point64(float xin, float s64, float bk8,
                                        v2f* __restrict__ accA,
                                        v2f* __restrict__ accB) {
    const float C1 = 0.60653065971f,    C2 = 0.13533528324f,
                C3 = 0.01110899654f,    C4 = 3.35462627903e-4f,
                C5 = 3.72665317208e-6f, C6 = 1.52299797447e-8f,
                C7 = 2.28973484833e-11f, C8 = 1.26641655490e-14f;
    const v2f c1 = {C1, C1}, c2 = {C2, C2}, c3 = {C3, C3}, c4 = {C4, C4},
              c5 = {C5, C5}, c6 = {C6, C6}, c7 = {C7, C7}, c8 = {C8, C8};
    float d   = fmaf(xin, s64, bk8);
    float dc  = __builtin_amdgcn_fmed3f(d, -30.0f, 78.0f);
    float x   = dc * L2E;
    float r   = __builtin_amdgcn_exp2f(x);
    float ri  = __builtin_amdgcn_exp2f(-x);
    float t1  = dc * QF;
    float A1  = __builtin_amdgcn_exp2f(-(t1 * t1));
    float t2  = fmaf(dc, QF, -16.0f * QF);
    float A2  = __builtin_amdgcn_exp2f(-(t2 * t2));
    float t3  = fmaf(dc, QF, -32.0f * QF);
    float A3  = __builtin_amdgcn_exp2f(-(t3 * t3));
    float t4  = fmaf(dc, QF, -48.0f * QF);
    float A4  = __builtin_amdgcn_exp2f(-(t4 * t4));
    v2f RRa = {r,        r * K16};
    v2f RRb = {r * K32,  r * K48};
    v2f RIa = {ri,       ri * K16I};
    v2f RIb = {ri * K32I, ri * K48I};
    v2f TA = {A1, A2}, TB = {A3, A4};
    v2f UA = TA, UB = TB;
    accA[8] += TA;  accB[8] += TB;                 // center bins (8,24,40,56)
    TA *= RRa; accA[9]  = __builtin_elementwise_fma(TA, c1, accA[9]);
    TB *= RRb; accB[9]  = __builtin_elementwise_fma(TB, c1, accB[9]);
    TA *= RRa; accA[10] = __builtin_elementwise_fma(TA, c2, accA[10]);
    TB *= RRb; accB[10] = __builtin_elementwise_fma(TB, c2, accB[10]);
    TA *= RRa; accA[11] = __builtin_elementwise_fma(TA, c3, accA[11]);
    TB *= RRb; accB[11] = __builtin_elementwise_fma(TB, c3, accB[11]);
    TA *= RRa; accA[12] = __builtin_elementwise_fma(TA, c4, accA[12]);
    TB *= RRb; accB[12] = __builtin_elementwise_fma(TB, c4, accB[12]);
    TA *= RRa; accA[13] = __builtin_elementwise_fma(TA, c5, accA[13]);
    TB *= RRb; accB[13] = __builtin_elementwise_fma(TB, c5, accB[13]);
    TA *= RRa; accA[14] = __builtin_elementwise_fma(TA, c6, accA[14]);
    TB *= RRb; accB[14] = __builtin_elementwise_fma(TB, c6, accB[14]);
    TA *= RRa; accA[15] = __builtin_elementwise_fma(TA, c7, accA[15]);
    TB *= RRb; accB[15] = __builtin_elementwise_fma(TB, c7, accB[15]);
    UA *= RIa; accA[7]  = __builtin_elementwise_fma(UA, c1, accA[7]);
    UB *= RIb; accB[7]  = __builtin_elementwise_fma(UB, c1, accB[7]);
    UA *= RIa; accA[6]  = __builtin_elementwise_fma(UA, c2, accA[6]);
    UB *= RIb; accB[6]  = __builtin_elementwise_fma(UB, c2, accB[6]);
    UA *= RIa; accA[5]  = __builtin_elementwise_fma(UA, c3, accA[5]);
    UB *= RIb; accB[5]  = __builtin_elementwise_fma(UB, c3, accB[5]);
    UA *= RIa; accA[4]  = __builtin_elementwise_fma(UA, c4, accA[4]);
    UB *= RIb; accB[4]  = __builtin_elementwise_fma(UB, c4, accB[4]);
    UA *= RIa; accA[3]  = __builtin_elementwise_fma(UA, c5, accA[3]);
    UB *= RIb; accB[3]  = __builtin_elementwise_fma(UB, c5, accB[3]);
    UA *= RIa; accA[2]  = __builtin_elementwise_fma(UA, c6, accA[2]);
    UB *= RIb; accB[2]  = __builtin_elementwise_fma(UB, c6, accB[2]);
    UA *= RIa; accA[1]  = __builtin_elementwise_fma(UA, c7, accA[1]);
    UB *= RIb; accB[1]  = __builtin_elementwise_fma(UB, c7, accB[1]);
    UA *= RIa; accA[0]  = __builtin_elementwise_fma(UA, c8, accA[0]);
    UB *= RIb; accB[0]  = __builtin_elementwise_fma(UB, c8, accB[0]);
}

// ---------- pass 2: gather histogram, 64 bins/wave, quarter-chunk/wave ----
__global__ __launch_bounds__(256, 2) void hist_k(const float4* __restrict__ pred,
                                                 const float4* __restrict__ tgt,
                                                 const float* __restrict__ mmn,
                                                 const float* __restrict__ mmx,
                                                 float* __restrict__ hist) {
    const int blk   = blockIdx.x;
    const int tens  = blk & 1;
    const int batch = (blk >> 1) & (NB - 1);
    const int chunk = blk >> 5;                      // 0..CB-1
    const int wave  = threadIdx.x >> 6, lane = threadIdx.x & 63;

    const int F4C = NPB / 4 / CB;                    // 1024 float4 per chunk
    const int F4Q = F4C / 4;                         // 256 per quarter (per wave)
    const float4* __restrict__ src = (tens ? tgt : pred)
        + (size_t)batch * (NPB / 4) + (size_t)chunk * F4C + (size_t)wave * F4Q;

    // issue first data load before the prologue reduction (overlap)
    float4 v = src[lane];

    // lane-parallel reduce of this batch's 64 minmax partials
    float vmin = mmn[batch * MMB + lane];
    float vmax = mmx[batch * MMB + lane];
    #pragma unroll
    for (int o = 1; o < 64; o <<= 1) {
        vmin = fminf(vmin, __shfl_xor(vmin, o));
        vmax = fmaxf(vmax, __shfl_xor(vmax, o));
    }
    const float s64 = 64.0f / (vmax - vmin + EPSF);
    const float bk8 = fmaf(-vmin, s64, -0.5f) - 8.0f;   // d = u - 8

    v2f accA[16], accB[16];
    #pragma unroll
    for (int k = 0; k < 16; ++k) {
        accA[k] = (v2f){0.0f, 0.0f};
        accB[k] = (v2f){0.0f, 0.0f};
    }

    const int NIT = F4Q / 64;                        // 4 wave-iterations
    #pragma unroll 1
    for (int it = 0; it < NIT; ++it) {
        // prefetch next iteration's data; latency hides under the burst
        float4 vn = src[(it < NIT - 1 ? (it + 1) * 64 : 0) + lane];
        point64(v.x, s64, bk8, accA, accB);
        point64(v.y, s64, bk8, accA, accB);
        point64(v.z, s64, bk8, accA, accB);
        point64(v.w, s64, bk8, accA, accB);
        v = vn;
    }

    // 6-step tree-exchange reduce over all 64 bins. Before step s:
    // val[i] = partial of bin ((i<<s) | (lane & (2^s-1))), summed over the
    // 2^s lanes matching in low s bits. Keep vk (bin matching this lane's
    // bit s), send vo (bin the partner keeps): val[p] = vk + shfl_xor(vo,o).
    // After step 5: val[0] = bin 'lane' summed over all 64 lanes.
    float val[64];
    #pragma unroll
    for (int k = 0; k < 16; ++k) {
        val[k]      = accA[k].x;   // bin k
        val[16 + k] = accA[k].y;   // bin 16+k
        val[32 + k] = accB[k].x;   // bin 32+k
        val[48 + k] = accB[k].y;   // bin 48+k
    }
    #pragma unroll
    for (int s = 0; s < 6; ++s) {
        const int o = 1 << s;
        const bool b = (lane >> s) & 1;
        #pragma unroll
        for (int p = 0; p < (32 >> s); ++p) {
            float lo = val[2 * p], hi = val[2 * p + 1];
            float vk = b ? hi : lo;          // bin this lane keeps
            float vo = b ? lo : hi;          // bin the partner keeps
            val[p] = vk + __shfl_xor(vo, o);
        }
    }
    unsafeAtomicAdd(&hist[(tens * NB + batch) * NBINS + lane], val[0]);
}

// ---------- pass 3: KL (fp32, v_log), tiny ----------
__global__ __launch_bounds__(256) void final_k(const float* __restrict__ hist,
                                               float* __restrict__ out) {
    const int lane = threadIdx.x & 63, wave = threadIdx.x >> 6;
    __shared__ float wacc[4];
    float a = 0.0f;
    for (int b = wave; b < NB; b += 4) {
        float hp = hist[b * NBINS + lane];
        float ht = hist[(NB + b) * NBINS + lane];
        float sp = hp, st = ht;
        #pragma unroll
        for (int o = 1; o < 64; o <<= 1) {
            sp += __shfl_xor(sp, o);
            st += __shfl_xor(st, o);
        }
        float pp = hp / (sp + EPSF);
        float pt = ht / (st + EPSF);
        float term = pt * ((__builtin_amdgcn_logf(pt + EPSF)
                          - __builtin_amdgcn_logf(pp + EPSF)) * LN2);
        #pragma unroll
        for (int o = 1; o < 64; o <<= 1) term += __shfl_xor(term, o);
        a += term;
    }
    if (lane == 0) wacc[wave] = a;
    __syncthreads();
    if (threadIdx.x == 0)
        out[0] = 0.1f * (wacc[0] + wacc[1] + wacc[2] + wacc[3]) / (float)NB;
}

extern "C" void kernel_launch(void* const* d_in, const int* in_sizes, int n_in,
                              void* d_out, int out_size, void* d_ws, size_t ws_size,
                              hipStream_t stream) {
    const float* pred = (const float*)d_in[0];
    const float* tgt  = (const float*)d_in[1];
    float* mmn  = (float*)d_ws;
    float* mmx  = mmn + NB * MMB;
    float* hist = mmx + NB * MMB;
    float* out  = (float*)d_out;

    minmax_k<<<NB * MMB, 256, 0, stream>>>((const float4*)tgt, mmn, mmx, hist);
    hist_k  <<<2 * NB * CB, 256, 0, stream>>>((const float4*)pred, (const float4*)tgt,
                                              mmn, mmx, hist);
    final_k <<<1, 256, 0, stream>>>(hist, out);
}

// Round 9
// 102.660 us; speedup vs baseline: 7.2467x; 1.0013x over previous
//
#include <hip/hip_runtime.h>
#include <math.h>

// Problem constants
#define NB    16            // batches
#define NPB   (512*512)     // elements per batch
#define NBINS 64
#define MMB   64            // minmax blocks per batch (grid 1024 = 4/CU)
#define CB    64            // hist chunks per (tensor,batch) -> grid 2*16*64 = 2048
#define EPSF  1e-8f
#define QF    0.84932180517f   // sqrt(0.5*log2(e)); exp(-d^2/2) = exp2(-(q*d)^2)
#define L2E   1.44269504089f   // log2(e)
#define LN2   0.69314718056f
#define K16   1.12535175e-7f   // e^-16
#define K16I  8886110.5f       // e^+16
#define K32   1.26641655e-14f  // e^-32
#define K32I  7.8962960e13f    // e^+32
#define K48   1.42516408e-21f  // e^-48
#define K48I  7.01673591e20f   // e^+48

// R26 = R25 single-visit 64-bin structure + occupancy restored. R25 at
// (256,2) was latency-bound: half the work of R22 at half R22's occupancy
// = wash (34 vs 34.5 us). Live-reg audit: acc 64 + rates 8 + temps 8 +
// v/vn 8 + scalars ~10 ~= 100 < 128 -> (256,4) fits without spill; 4
// waves/SIMD hides the ~4cyc chain-dependency stalls that 2 could not.
// Epilogue: tree step 0 fused into acc->val extraction (no 64-wide copy
// coexisting with live acc; same pairing -> bit-exact).
// Fixed in timed path: ~44 us harness ws re-poison; minmax ~7; final ~4;
// launch gaps ~14.

typedef float v2f __attribute__((ext_vector_type(2)));

// ws layout: mmn[1024] | mmx[1024] | hist[2][16][64]

// ---------- pass 1: per-batch block-level min/max (also zeroes hist) ----------
__global__ __launch_bounds__(256) void minmax_k(const float4* __restrict__ tgt,
                                                float* __restrict__ mmn,
                                                float* __restrict__ mmx,
                                                float* __restrict__ hist) {
    const int batch = blockIdx.x / MMB, sub = blockIdx.x % MMB;
    if (sub == 0 && threadIdx.x < 128) {
        const int tens = threadIdx.x >> 6, lane = threadIdx.x & 63;
        hist[(tens * NB + batch) * NBINS + lane] = 0.0f;
    }

    const int F4 = NPB / 4 / MMB;              // 1024 float4 per block
    const float4* p = tgt + (size_t)batch * (NPB / 4) + (size_t)sub * F4;
    float mn = 3.4e38f, mx = -3.4e38f;
    #pragma unroll
    for (int i = 0; i < F4 / 256; ++i) {       // 4 iterations
        float4 v = p[i * 256 + threadIdx.x];
        mn = fminf(mn, fminf(fminf(v.x, v.y), fminf(v.z, v.w)));
        mx = fmaxf(mx, fmaxf(fmaxf(v.x, v.y), fmaxf(v.z, v.w)));
    }
    #pragma unroll
    for (int o = 1; o < 64; o <<= 1) {
        mn = fminf(mn, __shfl_xor(mn, o));
        mx = fmaxf(mx, __shfl_xor(mx, o));
    }
    __shared__ float smn[4], smx[4];
    const int wave = threadIdx.x >> 6, lane = threadIdx.x & 63;
    if (lane == 0) { smn[wave] = mn; smx[wave] = mx; }
    __syncthreads();
    if (threadIdx.x == 0) {
        mmn[blockIdx.x] = fminf(fminf(smn[0], smn[1]), fminf(smn[2], smn[3]));
        mmx[blockIdx.x] = fmaxf(fmaxf(smx[0], smx[1]), fmaxf(smx[2], smx[3]));
    }
}

// ---------- per-point update of ALL 64 bins, 4 packed anchors ----------
// d = u - 8. Anchor m in {8,24,40,56} covers bins m-8..m+7:
// E(m+i) = A_m * rho_m^i * C_i, A_m = e^{-(d-(m-8))^2/2}, rho_m = e^d * e^{-(m-8)}.
// Packed pairs: A-array x/y = anchors (8,24); B-array x/y = anchors (40,56).
// accA[k] = bins (k, 16+k); accB[k] = bins (32+k, 48+k), k = 0..15.
// Clamp [-30,78]: at bounds max rate e^78 finite, amplitudes underflow to 0;
// clamp only bites where true contribution <= e^-242.
__device__ __forceinline__ void point64(float xin, float s64, float bk8,
                                        v2f* __restrict__ accA,
                                        v2f* __restrict__ accB) {
    const float C1 = 0.60653065971f,    C2 = 0.13533528324f,
                C3 = 0.01110899654f,    C4 = 3.35462627903e-4f,
                C5 = 3.72665317208e-6f, C6 = 1.52299797447e-8f,
                C7 = 2.28973484833e-11f, C8 = 1.26641655490e-14f;
    const v2f c1 = {C1, C1}, c2 = {C2, C2}, c3 = {C3, C3}, c4 = {C4, C4},
              c5 = {C5, C5}, c6 = {C6, C6}, c7 = {C7, C7}, c8 = {C8, C8};
    float d   = fmaf(xin, s64, bk8);
    float dc  = __builtin_amdgcn_fmed3f(d, -30.0f, 78.0f);
    float x   = dc * L2E;
    float r   = __builtin_amdgcn_exp2f(x);
    float ri  = __builtin_amdgcn_exp2f(-x);
    float t1  = dc * QF;
    float A1  = __builtin_amdgcn_exp2f(-(t1 * t1));
    float t2  = fmaf(dc, QF, -16.0f * QF);
    float A2  = __builtin_amdgcn_exp2f(-(t2 * t2));
    float t3  = fmaf(dc, QF, -32.0f * QF);
    float A3  = __builtin_amdgcn_exp2f(-(t3 * t3));
    float t4  = fmaf(dc, QF, -48.0f * QF);
    float A4  = __builtin_amdgcn_exp2f(-(t4 * t4));
    v2f RRa = {r,        r * K16};
    v2f RRb = {r * K32,  r * K48};
    v2f RIa = {ri,       ri * K16I};
    v2f RIb = {ri * K32I, ri * K48I};
    v2f TA = {A1, A2}, TB = {A3, A4};
    v2f UA = TA, UB = TB;
    accA[8] += TA;  accB[8] += TB;                 // center bins (8,24,40,56)
    TA *= RRa; accA[9]  = __builtin_elementwise_fma(TA, c1, accA[9]);
    TB *= RRb; accB[9]  = __builtin_elementwise_fma(TB, c1, accB[9]);
    TA *= RRa; accA[10] = __builtin_elementwise_fma(TA, c2, accA[10]);
    TB *= RRb; accB[10] = __builtin_elementwise_fma(TB, c2, accB[10]);
    TA *= RRa; accA[11] = __builtin_elementwise_fma(TA, c3, accA[11]);
    TB *= RRb; accB[11] = __builtin_elementwise_fma(TB, c3, accB[11]);
    TA *= RRa; accA[12] = __builtin_elementwise_fma(TA, c4, accA[12]);
    TB *= RRb; accB[12] = __builtin_elementwise_fma(TB, c4, accB[12]);
    TA *= RRa; accA[13] = __builtin_elementwise_fma(TA, c5, accA[13]);
    TB *= RRb; accB[13] = __builtin_elementwise_fma(TB, c5, accB[13]);
    TA *= RRa; accA[14] = __builtin_elementwise_fma(TA, c6, accA[14]);
    TB *= RRb; accB[14] = __builtin_elementwise_fma(TB, c6, accB[14]);
    TA *= RRa; accA[15] = __builtin_elementwise_fma(TA, c7, accA[15]);
    TB *= RRb; accB[15] = __builtin_elementwise_fma(TB, c7, accB[15]);
    UA *= RIa; accA[7]  = __builtin_elementwise_fma(UA, c1, accA[7]);
    UB *= RIb; accB[7]  = __builtin_elementwise_fma(UB, c1, accB[7]);
    UA *= RIa; accA[6]  = __builtin_elementwise_fma(UA, c2, accA[6]);
    UB *= RIb; accB[6]  = __builtin_elementwise_fma(UB, c2, accB[6]);
    UA *= RIa; accA[5]  = __builtin_elementwise_fma(UA, c3, accA[5]);
    UB *= RIb; accB[5]  = __builtin_elementwise_fma(UB, c3, accB[5]);
    UA *= RIa; accA[4]  = __builtin_elementwise_fma(UA, c4, accA[4]);
    UB *= RIb; accB[4]  = __builtin_elementwise_fma(UB, c4, accB[4]);
    UA *= RIa; accA[3]  = __builtin_elementwise_fma(UA, c5, accA[3]);
    UB *= RIb; accB[3]  = __builtin_elementwise_fma(UB, c5, accB[3]);
    UA *= RIa; accA[2]  = __builtin_elementwise_fma(UA, c6, accA[2]);
    UB *= RIb; accB[2]  = __builtin_elementwise_fma(UB, c6, accB[2]);
    UA *= RIa; accA[1]  = __builtin_elementwise_fma(UA, c7, accA[1]);
    UB *= RIb; accB[1]  = __builtin_elementwise_fma(UB, c7, accB[1]);
    UA *= RIa; accA[0]  = __builtin_elementwise_fma(UA, c8, accA[0]);
    UB *= RIb; accB[0]  = __builtin_elementwise_fma(UB, c8, accB[0]);
}

// ---------- pass 2: gather histogram, 64 bins/wave, quarter-chunk/wave ----
__global__ __launch_bounds__(256, 4) void hist_k(const float4* __restrict__ pred,
                                                 const float4* __restrict__ tgt,
                                                 const float* __restrict__ mmn,
                                                 const float* __restrict__ mmx,
                                                 float* __restrict__ hist) {
    const int blk   = blockIdx.x;
    const int tens  = blk & 1;
    const int batch = (blk >> 1) & (NB - 1);
    const int chunk = blk >> 5;                      // 0..CB-1
    const int wave  = threadIdx.x >> 6, lane = threadIdx.x & 63;

    const int F4C = NPB / 4 / CB;                    // 1024 float4 per chunk
    const int F4Q = F4C / 4;                         // 256 per quarter (per wave)
    const float4* __restrict__ src = (tens ? tgt : pred)
        + (size_t)batch * (NPB / 4) + (size_t)chunk * F4C + (size_t)wave * F4Q;

    // issue first data load before the prologue reduction (overlap)
    float4 v = src[lane];

    // lane-parallel reduce of this batch's 64 minmax partials
    float vmin = mmn[batch * MMB + lane];
    float vmax = mmx[batch * MMB + lane];
    #pragma unroll
    for (int o = 1; o < 64; o <<= 1) {
        vmin = fminf(vmin, __shfl_xor(vmin, o));
        vmax = fmaxf(vmax, __shfl_xor(vmax, o));
    }
    const float s64 = 64.0f / (vmax - vmin + EPSF);
    const float bk8 = fmaf(-vmin, s64, -0.5f) - 8.0f;   // d = u - 8

    v2f accA[16], accB[16];
    #pragma unroll
    for (int k = 0; k < 16; ++k) {
        accA[k] = (v2f){0.0f, 0.0f};
        accB[k] = (v2f){0.0f, 0.0f};
    }

    const int NIT = F4Q / 64;                        // 4 wave-iterations
    #pragma unroll 1
    for (int it = 0; it < NIT; ++it) {
        // prefetch next iteration's data; latency hides under the burst
        float4 vn = src[(it < NIT - 1 ? (it + 1) * 64 : 0) + lane];
        point64(v.x, s64, bk8, accA, accB);
        point64(v.y, s64, bk8, accA, accB);
        point64(v.z, s64, bk8, accA, accB);
        point64(v.w, s64, bk8, accA, accB);
        v = vn;
    }

    // 6-step tree-exchange reduce over all 64 bins; step 0 fused with the
    // acc->val extraction so no 64-wide copy coexists with live acc.
    // Bin map: accA[k].x = bin k, accA[k].y = bin 16+k, accB[k].x = bin
    // 32+k, accB[k].y = bin 48+k. Step 0 pairs bins (2p, 2p+1). Keep vk
    // (bin matching this lane's bit s), send vo (bin the partner keeps):
    // val[p] = vk + shfl_xor(vo, o). After step 5: val[0] = bin 'lane'.
    float val[32];
    {
        const bool b = lane & 1;
        #pragma unroll
        for (int p = 0; p < 8; ++p) {
            float lo, hi, vk, vo;
            lo = accA[2*p].x; hi = accA[2*p+1].x;       // bins (2p, 2p+1)
            vk = b ? hi : lo; vo = b ? lo : hi;
            val[p]      = vk + __shfl_xor(vo, 1);
            lo = accA[2*p].y; hi = accA[2*p+1].y;       // bins (16+2p, 17+2p)
            vk = b ? hi : lo; vo = b ? lo : hi;
            val[8 + p]  = vk + __shfl_xor(vo, 1);
            lo = accB[2*p].x; hi = accB[2*p+1].x;       // bins (32+2p, 33+2p)
            vk = b ? hi : lo; vo = b ? lo : hi;
            val[16 + p] = vk + __shfl_xor(vo, 1);
            lo = accB[2*p].y; hi = accB[2*p+1].y;       // bins (48+2p, 49+2p)
            vk = b ? hi : lo; vo = b ? lo : hi;
            val[24 + p] = vk + __shfl_xor(vo, 1);
        }
    }
    #pragma unroll
    for (int s = 1; s < 6; ++s) {
        const int o = 1 << s;
        const bool b = (lane >> s) & 1;
        #pragma unroll
        for (int p = 0; p < (32 >> s); ++p) {
            float lo = val[2 * p], hi = val[2 * p + 1];
            float vk = b ? hi : lo;          // bin this lane keeps
            float vo = b ? lo : hi;          // bin the partner keeps
            val[p] = vk + __shfl_xor(vo, o);
        }
    }
    unsafeAtomicAdd(&hist[(tens * NB + batch) * NBINS + lane], val[0]);
}

// ---------- pass 3: KL (fp32, v_log), tiny ----------
__global__ __launch_bounds__(256) void final_k(const float* __restrict__ hist,
                                               float* __restrict__ out) {
    const int lane = threadIdx.x & 63, wave = threadIdx.x >> 6;
    __shared__ float wacc[4];
    float a = 0.0f;
    for (int b = wave; b < NB; b += 4) {
        float hp = hist[b * NBINS + lane];
        float ht = hist[(NB + b) * NBINS + lane];
        float sp = hp, st = ht;
        #pragma unroll
        for (int o = 1; o < 64; o <<= 1) {
            sp += __shfl_xor(sp, o);
            st += __shfl_xor(st, o);
        }
        float pp = hp / (sp + EPSF);
        float pt = ht / (st + EPSF);
        float term = pt * ((__builtin_amdgcn_logf(pt + EPSF)
                          - __builtin_amdgcn_logf(pp + EPSF)) * LN2);
        #pragma unroll
        for (int o = 1; o < 64; o <<= 1) term += __shfl_xor(term, o);
        a += term;
    }
    if (lane == 0) wacc[wave] = a;
    __syncthreads();
    if (threadIdx.x == 0)
        out[0] = 0.1f * (wacc[0] + wacc[1] + wacc[2] + wacc[3]) / (float)NB;
}

extern "C" void kernel_launch(void* const* d_in, const int* in_sizes, int n_in,
                              void* d_out, int out_size, void* d_ws, size_t ws_size,
                              hipStream_t stream) {
    const float* pred = (const float*)d_in[0];
    const float* tgt  = (const float*)d_in[1];
    float* mmn  = (float*)d_ws;
    float* mmx  = mmn + NB * MMB;
    float* hist = mmx + NB * MMB;
    float* out  = (float*)d_out;

    minmax_k<<<NB * MMB, 256, 0, stream>>>((const float4*)tgt, mmn, mmx, hist);
    hist_k  <<<2 * NB * CB, 256, 0, stream>>>((const float4*)pred, (const float4*)tgt,
                                              mmn, mmx, hist);
    final_k <<<1, 256, 0, stream>>>(hist, out);
}